// Round 5
// baseline (59.842 us; speedup 1.0000x reference)
//
#include <hip/hip_runtime.h>
#include <hip/hip_bf16.h>

// Problem constants (match reference)
#define CIN_  128
#define H_    28
#define W_    28
#define COUT_ 32
#define B_    512
// GEMM view per (b,h): Y[32 x 28] = Wm[32 x 384] * Xwin[384 x 28]
// K order: kappa = tap*128 + channel, chunked in 12 chunks of 32.

typedef __attribute__((ext_vector_type(8))) short short8;  // 8 bf16 in 4 VGPRs
typedef __attribute__((ext_vector_type(4))) float f32x4;

__device__ __forceinline__ short f2bf(float f) {
    __hip_bfloat16 h = __float2bfloat16(f);    // RNE, single HW cvt
    union { __hip_bfloat16 h; short s; } u; u.h = h;
    return u.s;
}

// ---------------------------------------------------------------------------
// Pre-pass: build bf16 A-fragments of Wm in d_ws.
// Fragment f = mt*12 + kc  (mt: 0..1 M-tile of 16 couts, kc: 0..11 K-chunk of 32)
// Element (lane l, slot j): Wm[jo = mt*16 + (l&15)][i = (kc&3)*32 + (l>>4)*8 + j][tap = kc>>2]
// Stored flat: ws[f*512 + l*8 + j]  -> lane l loads 16B at f*1024 + l*16 bytes.
// ---------------------------------------------------------------------------
__global__ void prep_w_kernel(const float* __restrict__ w, short* __restrict__ wsA) {
    int t = blockIdx.x * 256 + threadIdx.x;      // 24*512 = 12288 threads
    int frag = t >> 9;
    int rem  = t & 511;
    int l = rem >> 3;
    int j = rem & 7;
    int mt = frag / 12;
    int kc = frag % 12;
    int tap = kc >> 2;
    int i  = (kc & 3) * 32 + (l >> 4) * 8 + j;
    int jo = mt * 16 + (l & 15);
    wsA[t] = f2bf(w[(jo * CIN_ + i) * 3 + tap]);
}

// ---------------------------------------------------------------------------
// Main kernel v5: 1-D grid of 3584 blocks, 256 threads (4 waves).
// XCD-bijective swizzle: hardware block B -> logical L = (B&7)*448 + (B>>3),
// so the 7 hg-blocks of each batch b (and 64 consecutive b) share one XCD's
// L2 -> 448-B segment boundary lines are fetched once.
// Wave wv computes row h = hg*4 + wv. Block-cooperative staging of the 4
// consecutive rows (448-B contiguous reads, all 14 f32x4 in flight), one
// barrier, per-wave GEMM from private LDS buffer, then accumulators are
// gathered in LDS and stored block-cooperatively as aligned f32x4 bursts
// (eliminates partial-cache-line RMW on the output).
// LDS per wave: x-row transposed [wt 0..29][128 ch] bf16, XOR-swizzled:
//   (wt, i) at short index  wt*128 + (((i>>3) ^ (wt&15))<<3 | (i&7))
// wt = w + tap (w_real = wt-1). Rows 0 and 29 zeroed (padding). B-reads with
// wt in 30..33 only feed discarded output cols (wcol >= 28); clamp to 29.
// ---------------------------------------------------------------------------
template<bool USE_WS>
__global__ __launch_bounds__(256, 5)
void conv_kernel(const float* __restrict__ x, const float* __restrict__ w,
                 const short* __restrict__ wsA, float* __restrict__ out) {
    __shared__ short lds[4][30 * CIN_];          // 4 x 7680 B = 30720 B
    const int tid = threadIdx.x;
    const int wv  = tid >> 6;
    const int l   = tid & 63;

    // ---- XCD-bijective block swizzle (nwg = 3584 = 8 * 448) ----
    const int Bid = blockIdx.x;
    const int L   = (Bid & 7) * 448 + (Bid >> 3);
    const int b   = L / 7;                       // 0..511
    const int hg  = L % 7;                       // 0..6
    const int h0  = hg * 4;

    const float* xb = x + (size_t)b * (CIN_ * H_ * W_);

    // ---- zero pad rows wt=0 and wt=29 in this wave's buffer ----
    {
        int s   = (tid & 63) * 4;                // 0..252
        int row = (s >= 128) ? 29 : 0;
        int c   = s & 127;
        *reinterpret_cast<ulong1*>(&lds[wv][row * CIN_ + c]) = ulong1{0};
    }

    // ---- block-cooperative staging: 128 ch x 28 quads (4 rows x 7) ----
    // All 14 loads issued before any convert/write (deep pipeline).
    f32x4 vb[14];
#pragma unroll
    for (int it = 0; it < 14; ++it) {
        int f4 = it * 256 + tid;                 // 0..3583
        int i  = f4 / 28;                        // channel
        int q  = f4 % 28;                        // quad within 448-B segment
        vb[it] = *reinterpret_cast<const f32x4*>(xb + i * (H_ * W_) + h0 * W_ + q * 4);
    }
#pragma unroll
    for (int it = 0; it < 14; ++it) {
        int f4 = it * 256 + tid;
        int i  = f4 / 28;
        int q  = f4 % 28;
        int hl = q / 7;                          // local row 0..3
        int w4 = q % 7;
        short* buf = lds[hl];
#pragma unroll
        for (int e = 0; e < 4; ++e) {
            int wt   = w4 * 4 + e + 1;           // 1..28
            int sidx = wt * CIN_ + ((((i >> 3) ^ (wt & 15)) << 3) | (i & 7));
            buf[sidx] = f2bf(vb[it][e]);
        }
    }
    __syncthreads();

    // ---- per-wave GEMM: 2 M-tiles x 2 N-tiles x 12 K-chunks of 32 ----
    short* wbuf = lds[wv];

    f32x4 acc[2][2];
#pragma unroll
    for (int mt = 0; mt < 2; ++mt)
#pragma unroll
        for (int nt = 0; nt < 2; ++nt)
#pragma unroll
            for (int q = 0; q < 4; ++q) acc[mt][nt][q] = 0.0f;

#pragma unroll
    for (int half = 0; half < 2; ++half) {
        short8 a0[6], a1[6];                     // 12 frags live = 48 VGPR
        if (USE_WS) {
#pragma unroll
            for (int k6 = 0; k6 < 6; ++k6) {
                int kc = half * 6 + k6;
                a0[k6] = *reinterpret_cast<const short8*>(wsA + kc * 512 + l * 8);
                a1[k6] = *reinterpret_cast<const short8*>(wsA + (12 + kc) * 512 + l * 8);
            }
        } else {
#pragma unroll
            for (int k6 = 0; k6 < 6; ++k6) {
                int kc  = half * 6 + k6;
                int tap = kc >> 2;
                int ib  = (kc & 3) * 32 + (l >> 4) * 8;
#pragma unroll
                for (int j = 0; j < 8; ++j) {
                    a0[k6][j] = f2bf(w[((l & 15) * CIN_ + ib + j) * 3 + tap]);
                    a1[k6][j] = f2bf(w[((16 + (l & 15)) * CIN_ + ib + j) * 3 + tap]);
                }
            }
        }
#pragma unroll
        for (int k6 = 0; k6 < 6; ++k6) {
            int kc  = half * 6 + k6;
            int tap = kc >> 2;
            int c   = (kc & 3) * 4 + (l >> 4);   // chunk index of lane's 8 channels
#pragma unroll
            for (int nt = 0; nt < 2; ++nt) {
                int wt  = nt * 16 + (l & 15) + tap;     // 0..33
                int wtc = wt > 29 ? 29 : wt;            // clamp: rows >29 feed dead cols
                const short8 bfrag = *reinterpret_cast<const short8*>(
                    &wbuf[wtc * CIN_ + ((c ^ (wtc & 15)) << 3)]);
                acc[0][nt] = __builtin_amdgcn_mfma_f32_16x16x32_bf16(
                    a0[k6], bfrag, acc[0][nt], 0, 0, 0);
                acc[1][nt] = __builtin_amdgcn_mfma_f32_16x16x32_bf16(
                    a1[k6], bfrag, acc[1][nt], 0, 0, 0);
            }
        }
    }
    __syncthreads();                             // all GEMM LDS reads done

    // ---- gather accumulators into LDS: arr[j 0..31][hl 0..3][w 0..27] ----
    float* arr = reinterpret_cast<float*>(&lds[0][0]);   // 14336 B reuse
#pragma unroll
    for (int mt = 0; mt < 2; ++mt)
#pragma unroll
        for (int nt = 0; nt < 2; ++nt)
#pragma unroll
            for (int rr = 0; rr < 4; ++rr) {
                int j    = mt * 16 + (l >> 4) * 4 + rr;
                int wcol = nt * 16 + (l & 15);
                if (wcol < W_)
                    arr[(j * 4 + wv) * W_ + wcol] = acc[mt][nt][rr];
            }
    __syncthreads();

    // ---- block-cooperative aligned f32x4 stores (with per-chunk roll) ----
    float* ob = out + (size_t)b * (COUT_ * H_ * W_);
#pragma unroll
    for (int it = 0; it < 4; ++it) {
        int c = it * 256 + tid;                  // 0..1023, valid < 896
        if (c < 896) {
            int j  = c / 28;                     // cout
            int q  = c % 28;
            int hl = q / 7;                      // local row
            int w4 = q % 7;
            int ho = h0 + hl + 1;
            if (ho >= H_) ho -= H_;
            f32x4 v = *reinterpret_cast<const f32x4*>(&arr[(j * 4 + hl) * W_ + w4 * 4]);
            *reinterpret_cast<f32x4*>(ob + (j * H_ + ho) * W_ + w4 * 4) = v;
        }
    }
}

extern "C" void kernel_launch(void* const* d_in, const int* in_sizes, int n_in,
                              void* d_out, int out_size, void* d_ws, size_t ws_size,
                              hipStream_t stream) {
    (void)in_sizes; (void)n_in; (void)out_size;
    const float* x = (const float*)d_in[0];
    const float* w = (const float*)d_in[1];
    float* out = (float*)d_out;

    if (ws_size >= (size_t)(24 * 512 * sizeof(short))) {
        short* wsA = (short*)d_ws;
        prep_w_kernel<<<dim3(48), dim3(256), 0, stream>>>(w, wsA);
        conv_kernel<true><<<dim3(3584), dim3(256), 0, stream>>>(x, w, wsA, out);
    } else {
        conv_kernel<false><<<dim3(3584), dim3(256), 0, stream>>>(x, w, (const short*)nullptr, out);
    }
}